// Round 1
// baseline (715.030 us; speedup 1.0000x reference)
//
#include <hip/hip_runtime.h>
#include <hip/hip_bf16.h>

#define T_TOKENS 2048
#define HID 1024
#define ISZ 1408
#define NEXP 8
#define RMAX 4608   // 4096 rows + per-expert 64-alignment padding

typedef __bf16 bf16x8 __attribute__((ext_vector_type(8)));
typedef float  f32x4  __attribute__((ext_vector_type(4)));

// ---------------- Router: one wave per token ----------------
__global__ __launch_bounds__(256) void router_kernel(
    const float* __restrict__ x, const float* __restrict__ gw,
    int* __restrict__ sel, float* __restrict__ wt, int* __restrict__ counts)
{
    __shared__ float sgw[HID * NEXP];  // 32 KB
    for (int i = threadIdx.x; i < HID * NEXP; i += 256) sgw[i] = gw[i];
    __syncthreads();

    const int wave = threadIdx.x >> 6;
    const int lane = threadIdx.x & 63;
    const int t = blockIdx.x * 4 + wave;
    const float* xr = x + (size_t)t * HID;

    const int e = lane & 7;        // expert
    const int c = lane >> 3;       // chunk 0..7 (128 h each)
    float acc = 0.f;
    #pragma unroll 4
    for (int h = c * 128; h < c * 128 + 128; ++h)
        acc += xr[h] * sgw[h * NEXP + e];
    // reduce across chunk lanes (same e): xor bits 3,4,5
    acc += __shfl_xor(acc, 8);
    acc += __shfl_xor(acc, 16);
    acc += __shfl_xor(acc, 32);
    // softmax over 8 experts (xor bits 0,1,2)
    float m = acc;
    #pragma unroll
    for (int d = 1; d < 8; d <<= 1) m = fmaxf(m, __shfl_xor(m, d));
    float p = expf(acc - m);
    float s = p;
    #pragma unroll
    for (int d = 1; d < 8; d <<= 1) s += __shfl_xor(s, d);
    p /= s;
    // top-1 (tie -> lower index, matches jax top_k)
    float p1 = p; int e1 = e;
    #pragma unroll
    for (int d = 1; d < 8; d <<= 1) {
        float op = __shfl_xor(p1, d); int oe = __shfl_xor(e1, d);
        if (op > p1 || (op == p1 && oe < e1)) { p1 = op; e1 = oe; }
    }
    // top-2
    float pm = (e == e1) ? -1.0f : p;
    float p2 = pm; int e2 = e;
    #pragma unroll
    for (int d = 1; d < 8; d <<= 1) {
        float op = __shfl_xor(p2, d); int oe = __shfl_xor(e2, d);
        if (op > p2 || (op == p2 && oe < e2)) { p2 = op; e2 = oe; }
    }
    if (lane == 0) {
        float inv = 1.0f / (p1 + p2);
        sel[t * 2 + 0] = e1; sel[t * 2 + 1] = e2;
        wt[t * 2 + 0] = p1 * inv; wt[t * 2 + 1] = p2 * inv;
        atomicAdd(&counts[e1], 1); atomicAdd(&counts[e2], 1);
    }
}

__global__ void scan_kernel(const int* __restrict__ counts, int* __restrict__ offs,
                            int* __restrict__ ncnt, int* __restrict__ cursor)
{
    if (threadIdx.x == 0 && blockIdx.x == 0) {
        int cur = 0;
        for (int e = 0; e < NEXP; ++e) {
            offs[e] = cur;
            int n = (counts[e] + 63) & ~63;
            ncnt[e] = n;
            cursor[e] = 0;
            cur += n;
        }
    }
}

__global__ __launch_bounds__(256) void assign_kernel(
    const int* __restrict__ sel, const float* __restrict__ wt,
    const int* __restrict__ offs, int* __restrict__ cursor,
    int* __restrict__ rtok, float* __restrict__ rwt)
{
    int t = blockIdx.x * 256 + threadIdx.x;
    if (t >= T_TOKENS) return;
    #pragma unroll
    for (int k = 0; k < 2; ++k) {
        int e = sel[t * 2 + k];
        int pos = atomicAdd(&cursor[e], 1);
        int row = offs[e] + pos;
        rtok[row] = t;
        rwt[row] = wt[t * 2 + k];
    }
}

// ---------------- FFN1: inter = silu(x@Wg) * (x@Wu), per-expert grouped GEMM ----------------
__global__ __launch_bounds__(256) void ffn1_kernel(
    const float* __restrict__ x,
    const float* __restrict__ wg_all, const float* __restrict__ wu_all,
    const int* __restrict__ rtok, const int* __restrict__ offs,
    const int* __restrict__ ncnt, __bf16* __restrict__ inter)
{
    const int e  = blockIdx.x >> 5;
    const int rt = blockIdx.x & 31;
    if (rt * 64 >= ncnt[e]) return;
    const int rowbase = offs[e] + rt * 64;
    const int i0 = blockIdx.y * 64;

    __shared__ __bf16 xa [64][40];
    __shared__ __bf16 wgT[64][40];   // [i][k] (transposed)
    __shared__ __bf16 wuT[64][40];

    const int tid = threadIdx.x;
    const int lane = tid & 63;
    const int wid  = tid >> 6;
    const int wr = wid >> 1, wc = wid & 1;   // wave quadrant of 64x64
    const int kh = lane >> 4;                // k-group 0..3
    const int ml = lane & 15;

    // x staging role: row = tid/4, 8 cols at (tid%4)*8
    const int lrow  = tid >> 2;
    const int lquad = tid & 3;
    const int tok = rtok[rowbase + lrow];
    const float* xrow = (tok >= 0) ? (x + (size_t)tok * HID) : nullptr;

    // weight staging role: k-row = tid/16 (two passes +16), 4 cols at (tid%16)*4
    const int kk  = tid >> 4;
    const int ii4 = (tid & 15) * 4;
    const float* wg_e = wg_all + (size_t)e * HID * ISZ;
    const float* wu_e = wu_all + (size_t)e * HID * ISZ;

    f32x4 accg[2][2]; f32x4 accu[2][2];
    #pragma unroll
    for (int a = 0; a < 2; ++a)
        #pragma unroll
        for (int b = 0; b < 2; ++b) { accg[a][b] = (f32x4){0,0,0,0}; accu[a][b] = (f32x4){0,0,0,0}; }

    for (int k0 = 0; k0 < HID; k0 += 32) {
        float xv[8] = {0,0,0,0,0,0,0,0};
        if (xrow) {
            float4 a = *(const float4*)(xrow + k0 + lquad * 8);
            float4 b = *(const float4*)(xrow + k0 + lquad * 8 + 4);
            xv[0]=a.x; xv[1]=a.y; xv[2]=a.z; xv[3]=a.w;
            xv[4]=b.x; xv[5]=b.y; xv[6]=b.z; xv[7]=b.w;
        }
        float4 g0 = *(const float4*)(wg_e + (size_t)(k0 + kk)      * ISZ + i0 + ii4);
        float4 g1 = *(const float4*)(wg_e + (size_t)(k0 + kk + 16) * ISZ + i0 + ii4);
        float4 u0 = *(const float4*)(wu_e + (size_t)(k0 + kk)      * ISZ + i0 + ii4);
        float4 u1 = *(const float4*)(wu_e + (size_t)(k0 + kk + 16) * ISZ + i0 + ii4);
        float ga[4] = {g0.x,g0.y,g0.z,g0.w}, gb[4] = {g1.x,g1.y,g1.z,g1.w};
        float ua[4] = {u0.x,u0.y,u0.z,u0.w}, ub[4] = {u1.x,u1.y,u1.z,u1.w};

        __syncthreads();   // previous iteration's LDS reads done
        {
            __bf16* xd = &xa[lrow][lquad * 8];
            #pragma unroll
            for (int j = 0; j < 8; ++j) xd[j] = (__bf16)xv[j];
            #pragma unroll
            for (int j = 0; j < 4; ++j) {
                wgT[ii4 + j][kk]      = (__bf16)ga[j];
                wgT[ii4 + j][kk + 16] = (__bf16)gb[j];
                wuT[ii4 + j][kk]      = (__bf16)ua[j];
                wuT[ii4 + j][kk + 16] = (__bf16)ub[j];
            }
        }
        __syncthreads();

        bf16x8 a0 = *(const bf16x8*)&xa [wr*32      + ml][kh*8];
        bf16x8 a1 = *(const bf16x8*)&xa [wr*32 + 16 + ml][kh*8];
        bf16x8 bg0 = *(const bf16x8*)&wgT[wc*32      + ml][kh*8];
        bf16x8 bg1 = *(const bf16x8*)&wgT[wc*32 + 16 + ml][kh*8];
        bf16x8 bu0 = *(const bf16x8*)&wuT[wc*32      + ml][kh*8];
        bf16x8 bu1 = *(const bf16x8*)&wuT[wc*32 + 16 + ml][kh*8];

        accg[0][0] = __builtin_amdgcn_mfma_f32_16x16x32_bf16(a0, bg0, accg[0][0], 0, 0, 0);
        accg[0][1] = __builtin_amdgcn_mfma_f32_16x16x32_bf16(a0, bg1, accg[0][1], 0, 0, 0);
        accg[1][0] = __builtin_amdgcn_mfma_f32_16x16x32_bf16(a1, bg0, accg[1][0], 0, 0, 0);
        accg[1][1] = __builtin_amdgcn_mfma_f32_16x16x32_bf16(a1, bg1, accg[1][1], 0, 0, 0);
        accu[0][0] = __builtin_amdgcn_mfma_f32_16x16x32_bf16(a0, bu0, accu[0][0], 0, 0, 0);
        accu[0][1] = __builtin_amdgcn_mfma_f32_16x16x32_bf16(a0, bu1, accu[0][1], 0, 0, 0);
        accu[1][0] = __builtin_amdgcn_mfma_f32_16x16x32_bf16(a1, bu0, accu[1][0], 0, 0, 0);
        accu[1][1] = __builtin_amdgcn_mfma_f32_16x16x32_bf16(a1, bu1, accu[1][1], 0, 0, 0);
    }

    // epilogue: silu(g)*u -> bf16 inter
    #pragma unroll
    for (int mf = 0; mf < 2; ++mf)
        #pragma unroll
        for (int nf = 0; nf < 2; ++nf)
            #pragma unroll
            for (int r = 0; r < 4; ++r) {
                float g = accg[mf][nf][r];
                float u = accu[mf][nf][r];
                float v = g / (1.0f + __expf(-g)) * u;
                int rloc = wr * 32 + mf * 16 + kh * 4 + r;   // D row = (lane>>4)*4 + reg
                int iloc = wc * 32 + nf * 16 + ml;           // D col = lane&15
                inter[(size_t)(rowbase + rloc) * ISZ + i0 + iloc] = (__bf16)v;
            }
}

// ---------------- FFN2: out[tok] += rwt * (inter @ Wd) ----------------
__global__ __launch_bounds__(256) void ffn2_kernel(
    const __bf16* __restrict__ inter, const float* __restrict__ wd_all,
    const int* __restrict__ rtok, const float* __restrict__ rwt,
    const int* __restrict__ offs, const int* __restrict__ ncnt,
    float* __restrict__ out)
{
    const int e  = blockIdx.x >> 5;
    const int rt = blockIdx.x & 31;
    if (rt * 64 >= ncnt[e]) return;
    const int rowbase = offs[e] + rt * 64;
    const int n0 = blockIdx.y * 64;

    __shared__ __bf16 xa [64][40];
    __shared__ __bf16 wdT[64][40];   // [n][k]

    const int tid = threadIdx.x;
    const int lane = tid & 63;
    const int wid  = tid >> 6;
    const int wr = wid >> 1, wc = wid & 1;
    const int kh = lane >> 4;
    const int ml = lane & 15;

    const int lrow  = tid >> 2;
    const int lquad = tid & 3;
    const __bf16* arow = inter + (size_t)(rowbase + lrow) * ISZ;

    const int kk  = tid >> 4;
    const int nn4 = (tid & 15) * 4;
    const float* wd_e = wd_all + (size_t)e * ISZ * HID;

    f32x4 acc[2][2];
    #pragma unroll
    for (int a = 0; a < 2; ++a)
        #pragma unroll
        for (int b = 0; b < 2; ++b) acc[a][b] = (f32x4){0,0,0,0};

    for (int k0 = 0; k0 < ISZ; k0 += 32) {
        bf16x8 av = *(const bf16x8*)(arow + k0 + lquad * 8);
        float4 d0 = *(const float4*)(wd_e + (size_t)(k0 + kk)      * HID + n0 + nn4);
        float4 d1 = *(const float4*)(wd_e + (size_t)(k0 + kk + 16) * HID + n0 + nn4);
        float da[4] = {d0.x,d0.y,d0.z,d0.w}, db[4] = {d1.x,d1.y,d1.z,d1.w};

        __syncthreads();
        *(bf16x8*)&xa[lrow][lquad * 8] = av;
        #pragma unroll
        for (int j = 0; j < 4; ++j) {
            wdT[nn4 + j][kk]      = (__bf16)da[j];
            wdT[nn4 + j][kk + 16] = (__bf16)db[j];
        }
        __syncthreads();

        bf16x8 a0 = *(const bf16x8*)&xa [wr*32      + ml][kh*8];
        bf16x8 a1 = *(const bf16x8*)&xa [wr*32 + 16 + ml][kh*8];
        bf16x8 b0 = *(const bf16x8*)&wdT[wc*32      + ml][kh*8];
        bf16x8 b1 = *(const bf16x8*)&wdT[wc*32 + 16 + ml][kh*8];

        acc[0][0] = __builtin_amdgcn_mfma_f32_16x16x32_bf16(a0, b0, acc[0][0], 0, 0, 0);
        acc[0][1] = __builtin_amdgcn_mfma_f32_16x16x32_bf16(a0, b1, acc[0][1], 0, 0, 0);
        acc[1][0] = __builtin_amdgcn_mfma_f32_16x16x32_bf16(a1, b0, acc[1][0], 0, 0, 0);
        acc[1][1] = __builtin_amdgcn_mfma_f32_16x16x32_bf16(a1, b1, acc[1][1], 0, 0, 0);
    }

    #pragma unroll
    for (int mf = 0; mf < 2; ++mf)
        #pragma unroll
        for (int nf = 0; nf < 2; ++nf)
            #pragma unroll
            for (int r = 0; r < 4; ++r) {
                int row = rowbase + wr * 32 + mf * 16 + kh * 4 + r;
                int tokr = rtok[row];
                if (tokr >= 0) {
                    float v = rwt[row] * acc[mf][nf][r];
                    atomicAdd(&out[(size_t)tokr * HID + n0 + wc * 32 + nf * 16 + ml], v);
                }
            }
}

extern "C" void kernel_launch(void* const* d_in, const int* in_sizes, int n_in,
                              void* d_out, int out_size, void* d_ws, size_t ws_size,
                              hipStream_t stream) {
    const float* x  = (const float*)d_in[0];
    const float* gw = (const float*)d_in[1];
    const float* wg = (const float*)d_in[2];
    const float* wu = (const float*)d_in[3];
    const float* wd = (const float*)d_in[4];
    float* out = (float*)d_out;

    char* ws = (char*)d_ws;
    int*   counts = (int*)(ws + 0);
    int*   cursor = (int*)(ws + 32);
    int*   offs   = (int*)(ws + 64);
    int*   ncnt   = (int*)(ws + 96);
    int*   sel    = (int*)(ws + 128);                      // 4096 int
    float* wtp    = (float*)(ws + 128 + 16384);            // 4096 float
    int*   rtok   = (int*)(ws + 128 + 32768);              // RMAX int
    float* rwt    = (float*)(ws + 128 + 32768 + 18432);    // RMAX float
    __bf16* inter = (__bf16*)(ws + 128 + 32768 + 36864);   // RMAX*ISZ bf16 (~13 MB)

    hipMemsetAsync(counts, 0, 32, stream);
    hipMemsetAsync(rtok, 0xFF, RMAX * 4, stream);
    hipMemsetAsync(out, 0, (size_t)T_TOKENS * HID * 4, stream);

    router_kernel<<<T_TOKENS / 4, 256, 0, stream>>>(x, gw, sel, wtp, counts);
    scan_kernel<<<1, 64, 0, stream>>>(counts, offs, ncnt, cursor);
    assign_kernel<<<(T_TOKENS + 255) / 256, 256, 0, stream>>>(sel, wtp, offs, cursor, rtok, rwt);
    ffn1_kernel<<<dim3(NEXP * 32, ISZ / 64), 256, 0, stream>>>(x, wg, wu, rtok, offs, ncnt, inter);
    ffn2_kernel<<<dim3(NEXP * 32, HID / 64), 256, 0, stream>>>(inter, wd, rtok, rwt, offs, ncnt, out);
}

// Round 2
// 539.595 us; speedup vs baseline: 1.3251x; 1.3251x over previous
//
#include <hip/hip_runtime.h>
#include <hip/hip_bf16.h>

#define T_TOKENS 2048
#define HID 1024
#define ISZ 1408
#define NEXP 8
#define RROWS 5120   // 4096 rows + per-expert 128-alignment padding

typedef __bf16 bf16x8 __attribute__((ext_vector_type(8)));
typedef __bf16 bf16x4 __attribute__((ext_vector_type(4)));
typedef float  f32x4  __attribute__((ext_vector_type(4)));

__device__ __forceinline__ void gload16(const void* g, void* l) {
    __builtin_amdgcn_global_load_lds(
        (const __attribute__((address_space(1))) void*)g,
        (__attribute__((address_space(3))) void*)l,
        16, 0, 0);
}

// ---------------- Router: one wave per token ----------------
__global__ __launch_bounds__(256) void router_kernel(
    const float* __restrict__ x, const float* __restrict__ gw,
    int* __restrict__ sel, float* __restrict__ wt, int* __restrict__ counts)
{
    __shared__ float sgw[HID * NEXP];  // 32 KB
    for (int i = threadIdx.x; i < HID * NEXP; i += 256) sgw[i] = gw[i];
    __syncthreads();

    const int wave = threadIdx.x >> 6;
    const int lane = threadIdx.x & 63;
    const int t = blockIdx.x * 4 + wave;
    const float* xr = x + (size_t)t * HID;

    const int e = lane & 7;        // expert
    const int c = lane >> 3;       // chunk 0..7 (128 h each)
    float acc = 0.f;
    #pragma unroll 4
    for (int h = c * 128; h < c * 128 + 128; ++h)
        acc += xr[h] * sgw[h * NEXP + e];
    acc += __shfl_xor(acc, 8);
    acc += __shfl_xor(acc, 16);
    acc += __shfl_xor(acc, 32);
    float m = acc;
    #pragma unroll
    for (int d = 1; d < 8; d <<= 1) m = fmaxf(m, __shfl_xor(m, d));
    float p = expf(acc - m);
    float s = p;
    #pragma unroll
    for (int d = 1; d < 8; d <<= 1) s += __shfl_xor(s, d);
    p /= s;
    float p1 = p; int e1 = e;
    #pragma unroll
    for (int d = 1; d < 8; d <<= 1) {
        float op = __shfl_xor(p1, d); int oe = __shfl_xor(e1, d);
        if (op > p1 || (op == p1 && oe < e1)) { p1 = op; e1 = oe; }
    }
    float pm = (e == e1) ? -1.0f : p;
    float p2 = pm; int e2 = e;
    #pragma unroll
    for (int d = 1; d < 8; d <<= 1) {
        float op = __shfl_xor(p2, d); int oe = __shfl_xor(e2, d);
        if (op > p2 || (op == p2 && oe < e2)) { p2 = op; e2 = oe; }
    }
    if (lane == 0) {
        float inv = 1.0f / (p1 + p2);
        sel[t * 2 + 0] = e1; sel[t * 2 + 1] = e2;
        wt[t * 2 + 0] = p1 * inv; wt[t * 2 + 1] = p2 * inv;
        atomicAdd(&counts[e1], 1); atomicAdd(&counts[e2], 1);
    }
}

__global__ void scan_kernel(const int* __restrict__ counts, int* __restrict__ offs,
                            int* __restrict__ ncnt, int* __restrict__ cursor)
{
    if (threadIdx.x == 0 && blockIdx.x == 0) {
        int cur = 0;
        for (int e = 0; e < NEXP; ++e) {
            offs[e] = cur;
            int n = (counts[e] + 127) & ~127;   // 128-row tile alignment
            ncnt[e] = n;
            cursor[e] = 0;
            cur += n;
        }
    }
}

__global__ __launch_bounds__(256) void assign_kernel(
    const int* __restrict__ sel, const float* __restrict__ wt,
    const int* __restrict__ offs, int* __restrict__ cursor,
    int* __restrict__ rtok, float* __restrict__ rwt)
{
    int t = blockIdx.x * 256 + threadIdx.x;
    if (t >= T_TOKENS) return;
    #pragma unroll
    for (int k = 0; k < 2; ++k) {
        int e = sel[t * 2 + k];
        int pos = atomicAdd(&cursor[e], 1);
        int row = offs[e] + pos;
        rtok[row] = t;
        rwt[row] = wt[t * 2 + k];
    }
}

// ---------------- Gather compacted token rows, fp32 -> bf16 ----------------
__global__ __launch_bounds__(256) void gather_kernel(
    const float* __restrict__ x, const int* __restrict__ rtok, __bf16* __restrict__ xg)
{
    const int row = blockIdx.x;
    const int tid = threadIdx.x;
    const int tok = rtok[row];
    bf16x4 o;
    if (tok >= 0) {
        float4 v = *(const float4*)(x + (size_t)tok * HID + tid * 4);
        o[0] = (__bf16)v.x; o[1] = (__bf16)v.y; o[2] = (__bf16)v.z; o[3] = (__bf16)v.w;
    } else {
        o[0] = (__bf16)0.f; o[1] = (__bf16)0.f; o[2] = (__bf16)0.f; o[3] = (__bf16)0.f;
    }
    *(bf16x4*)(xg + (size_t)row * HID + tid * 4) = o;
}

// ---------------- Transpose + convert: in fp32 [E][R][C] -> out bf16 [E][C][R] ----------------
__global__ __launch_bounds__(256) void tcvt_kernel(
    const float* __restrict__ in, __bf16* __restrict__ out, int R, int C)
{
    const int e = blockIdx.z;
    const float* ine = in + (size_t)e * R * C;
    __bf16* oute = out + (size_t)e * R * C;
    const int r0 = blockIdx.y * 64, c0 = blockIdx.x * 64;
    __shared__ float t[64][65];
    const int tid = threadIdx.x;
    const int lr  = tid >> 4;          // 0..15
    const int lc4 = (tid & 15) * 4;
    #pragma unroll
    for (int p = 0; p < 4; ++p) {
        float4 v = *(const float4*)(ine + (size_t)(r0 + p * 16 + lr) * C + c0 + lc4);
        t[p * 16 + lr][lc4 + 0] = v.x;
        t[p * 16 + lr][lc4 + 1] = v.y;
        t[p * 16 + lr][lc4 + 2] = v.z;
        t[p * 16 + lr][lc4 + 3] = v.w;
    }
    __syncthreads();
    #pragma unroll
    for (int p = 0; p < 4; ++p) {
        int oc = p * 16 + lr;          // local in-col index = out-row
        bf16x4 w;
        #pragma unroll
        for (int j = 0; j < 4; ++j) w[j] = (__bf16)t[lc4 + j][oc];
        *(bf16x4*)(oute + (size_t)(c0 + oc) * R + r0 + lc4) = w;
    }
}

// ---------------- FFN1: inter = silu(xg@WgT') * (xg@WuT'), m97-style grouped GEMM ----------------
// tile: BM=128 x BN=64 (both gate & up), BK=32, 4 waves in 2x2
__global__ __launch_bounds__(256) void ffn1_kernel(
    const __bf16* __restrict__ xg,
    const __bf16* __restrict__ wgT, const __bf16* __restrict__ wuT,
    const int* __restrict__ offs, const int* __restrict__ ncnt,
    __bf16* __restrict__ inter)
{
    const int e  = blockIdx.x >> 5;
    const int rt = blockIdx.x & 31;
    if (rt * 128 >= ncnt[e]) return;
    const int rowbase = offs[e] + rt * 128;
    const int i0 = blockIdx.y * 64;

    __shared__ __bf16 sA[128][32];  // 8 KB
    __shared__ __bf16 sG[64][32];   // 4 KB
    __shared__ __bf16 sU[64][32];   // 4 KB

    const int tid  = threadIdx.x;
    const int lane = tid & 63;
    const int wid  = tid >> 6;
    const int wr = wid >> 1, wc = wid & 1;
    const int kh = lane >> 4;
    const int ml = lane & 15;

    // staging: per-lane global addresses, wave-uniform LDS bases (linear, lane*16B)
    const int srow = lane >> 2;          // 0..15
    const int scol = (lane & 3) * 8;     // bf16 elems
    const __bf16* Ab = xg + (size_t)(rowbase + wid * 32 + srow) * HID + scol;
    const size_t wgoff = (size_t)e * ISZ * HID + (size_t)(i0 + wid * 16 + srow) * HID + scol;
    const __bf16* Gb = wgT + wgoff;
    const __bf16* Ub = wuT + wgoff;
    __bf16* ldsA0 = &sA[wid * 32][0];
    __bf16* ldsA1 = &sA[wid * 32 + 16][0];
    __bf16* ldsG  = &sG[wid * 16][0];
    __bf16* ldsU  = &sU[wid * 16][0];

    f32x4 accg[4][2], accu[4][2];
    #pragma unroll
    for (int m = 0; m < 4; ++m)
        #pragma unroll
        for (int n = 0; n < 2; ++n) { accg[m][n] = (f32x4){0,0,0,0}; accu[m][n] = (f32x4){0,0,0,0}; }

    for (int k0 = 0; k0 < HID; k0 += 32) {
        gload16(Ab + k0, ldsA0);
        gload16(Ab + k0 + (size_t)16 * HID, ldsA1);
        gload16(Gb + k0, ldsG);
        gload16(Ub + k0, ldsU);
        __syncthreads();   // drains vmcnt(0) -> LDS tiles ready

        bf16x8 a[4], g[2], u[2];
        #pragma unroll
        for (int m = 0; m < 4; ++m) a[m] = *(const bf16x8*)&sA[wr * 64 + m * 16 + ml][kh * 8];
        #pragma unroll
        for (int n = 0; n < 2; ++n) {
            g[n] = *(const bf16x8*)&sG[wc * 32 + n * 16 + ml][kh * 8];
            u[n] = *(const bf16x8*)&sU[wc * 32 + n * 16 + ml][kh * 8];
        }
        #pragma unroll
        for (int m = 0; m < 4; ++m)
            #pragma unroll
            for (int n = 0; n < 2; ++n) {
                accg[m][n] = __builtin_amdgcn_mfma_f32_16x16x32_bf16(a[m], g[n], accg[m][n], 0, 0, 0);
                accu[m][n] = __builtin_amdgcn_mfma_f32_16x16x32_bf16(a[m], u[n], accu[m][n], 0, 0, 0);
            }
        __syncthreads();   // all reads done before next overwrite
    }

    #pragma unroll
    for (int m = 0; m < 4; ++m)
        #pragma unroll
        for (int n = 0; n < 2; ++n)
            #pragma unroll
            for (int r = 0; r < 4; ++r) {
                float gv = accg[m][n][r];
                float uv = accu[m][n][r];
                float v = gv / (1.0f + __expf(-gv)) * uv;
                int row = rowbase + wr * 64 + m * 16 + kh * 4 + r;  // D row = (lane>>4)*4 + reg
                int col = i0 + wc * 32 + n * 16 + ml;               // D col = lane&15
                inter[(size_t)row * ISZ + col] = (__bf16)v;
            }
}

// ---------------- FFN2: out[tok] += rwt * (inter @ WdT') ----------------
__global__ __launch_bounds__(256) void ffn2_kernel(
    const __bf16* __restrict__ inter, const __bf16* __restrict__ wdT,
    const int* __restrict__ rtok, const float* __restrict__ rwt,
    const int* __restrict__ offs, const int* __restrict__ ncnt,
    float* __restrict__ out)
{
    const int e  = blockIdx.x >> 5;
    const int rt = blockIdx.x & 31;
    if (rt * 128 >= ncnt[e]) return;
    const int rowbase = offs[e] + rt * 128;
    const int n0 = blockIdx.y * 64;

    __shared__ __bf16 sA[128][32];
    __shared__ __bf16 sB[64][32];

    const int tid  = threadIdx.x;
    const int lane = tid & 63;
    const int wid  = tid >> 6;
    const int wr = wid >> 1, wc = wid & 1;
    const int kh = lane >> 4;
    const int ml = lane & 15;

    const int srow = lane >> 2;
    const int scol = (lane & 3) * 8;
    const __bf16* Ab = inter + (size_t)(rowbase + wid * 32 + srow) * ISZ + scol;
    const __bf16* Bb = wdT + (size_t)e * HID * ISZ + (size_t)(n0 + wid * 16 + srow) * ISZ + scol;
    __bf16* ldsA0 = &sA[wid * 32][0];
    __bf16* ldsA1 = &sA[wid * 32 + 16][0];
    __bf16* ldsB  = &sB[wid * 16][0];

    f32x4 acc[4][2];
    #pragma unroll
    for (int m = 0; m < 4; ++m)
        #pragma unroll
        for (int n = 0; n < 2; ++n) acc[m][n] = (f32x4){0,0,0,0};

    for (int k0 = 0; k0 < ISZ; k0 += 32) {
        gload16(Ab + k0, ldsA0);
        gload16(Ab + k0 + (size_t)16 * ISZ, ldsA1);
        gload16(Bb + k0, ldsB);
        __syncthreads();

        bf16x8 a[4], b[2];
        #pragma unroll
        for (int m = 0; m < 4; ++m) a[m] = *(const bf16x8*)&sA[wr * 64 + m * 16 + ml][kh * 8];
        #pragma unroll
        for (int n = 0; n < 2; ++n) b[n] = *(const bf16x8*)&sB[wc * 32 + n * 16 + ml][kh * 8];
        #pragma unroll
        for (int m = 0; m < 4; ++m)
            #pragma unroll
            for (int n = 0; n < 2; ++n)
                acc[m][n] = __builtin_amdgcn_mfma_f32_16x16x32_bf16(a[m], b[n], acc[m][n], 0, 0, 0);
        __syncthreads();
    }

    #pragma unroll
    for (int m = 0; m < 4; ++m)
        #pragma unroll
        for (int n = 0; n < 2; ++n)
            #pragma unroll
            for (int r = 0; r < 4; ++r) {
                int row = rowbase + wr * 64 + m * 16 + kh * 4 + r;
                int tokr = rtok[row];
                if (tokr >= 0) {
                    float v = rwt[row] * acc[m][n][r];
                    atomicAdd(&out[(size_t)tokr * HID + n0 + wc * 32 + n * 16 + ml], v);
                }
            }
}

extern "C" void kernel_launch(void* const* d_in, const int* in_sizes, int n_in,
                              void* d_out, int out_size, void* d_ws, size_t ws_size,
                              hipStream_t stream) {
    const float* x  = (const float*)d_in[0];
    const float* gw = (const float*)d_in[1];
    const float* wg = (const float*)d_in[2];
    const float* wu = (const float*)d_in[3];
    const float* wd = (const float*)d_in[4];
    float* out = (float*)d_out;

    char* ws = (char*)d_ws;
    int*    counts = (int*)(ws + 0);
    int*    cursor = (int*)(ws + 32);
    int*    offs   = (int*)(ws + 64);
    int*    ncnt   = (int*)(ws + 96);
    int*    sel    = (int*)(ws + 128);                  // 2048*2 int  = 16 KB
    float*  wtp    = (float*)(ws + 16512);              // 2048*2 f32  = 16 KB
    int*    rtok   = (int*)(ws + 32896);                // 5120 int    = 20 KB
    float*  rwt    = (float*)(ws + 53376);              // 5120 f32    = 20 KB
    __bf16* xg     = (__bf16*)(ws + 73856);             // 5120*1024 bf16 = 10.5 MB
    __bf16* inter  = (__bf16*)(ws + 10559616);          // 5120*1408 bf16 = 14.4 MB
    __bf16* wgT    = (__bf16*)(ws + 24977536);          // 8*1408*1024 bf16 = 23.1 MB
    __bf16* wuT    = (__bf16*)(ws + 48046208);          // 23.1 MB
    __bf16* wdT    = (__bf16*)(ws + 71114880);          // 23.1 MB -> total ~94.2 MB

    hipMemsetAsync(counts, 0, 32, stream);
    hipMemsetAsync(rtok, 0xFF, RROWS * 4, stream);
    hipMemsetAsync(out, 0, (size_t)T_TOKENS * HID * 4, stream);

    // weight convert+transpose (independent of router)
    tcvt_kernel<<<dim3(ISZ / 64, HID / 64, NEXP), 256, 0, stream>>>(wg, wgT, HID, ISZ);
    tcvt_kernel<<<dim3(ISZ / 64, HID / 64, NEXP), 256, 0, stream>>>(wu, wuT, HID, ISZ);
    tcvt_kernel<<<dim3(HID / 64, ISZ / 64, NEXP), 256, 0, stream>>>(wd, wdT, ISZ, HID);

    router_kernel<<<T_TOKENS / 4, 256, 0, stream>>>(x, gw, sel, wtp, counts);
    scan_kernel<<<1, 64, 0, stream>>>(counts, offs, ncnt, cursor);
    assign_kernel<<<(T_TOKENS + 255) / 256, 256, 0, stream>>>(sel, wtp, offs, cursor, rtok, rwt);
    gather_kernel<<<RROWS, 256, 0, stream>>>(x, rtok, xg);

    ffn1_kernel<<<dim3(NEXP * 32, ISZ / 64), 256, 0, stream>>>(xg, wgT, wuT, offs, ncnt, inter);
    ffn2_kernel<<<dim3(NEXP * 32, HID / 64), 256, 0, stream>>>(inter, wdT, rtok, rwt, offs, ncnt, out);
}